// Round 6
// baseline (425.099 us; speedup 1.0000x reference)
//
#include <hip/hip_runtime.h>

#define M_ROWS 16384
#define DIMX   1024
#define CD     12
#define KCB    4096
#define PADW   60   // padded dwords per float4-position fragment (48 data + 12 pad)

// ---------- Kernel A: h = x @ W_in + b_in ; writes h and oidx ----------
// Arithmetic (FMA order k,e,d; butterfly ofs 1..32; +bin at end) is bit-identical
// to the round-1/2 version that produced exact index match.
__global__ __launch_bounds__(256, 2) void k_hproj(
    const float* __restrict__ x, const float* __restrict__ Win,
    const float* __restrict__ bin, float* __restrict__ h, float* __restrict__ oidx)
{
  __shared__ __align__(16) float w[256 * PADW];   // 60 KB, conflict-free stride
  for (int f = threadIdx.x; f < 256 * 12; f += 256) {
    const int P = f / 12, c = f % 12;
    float4 v = reinterpret_cast<const float4*>(Win)[f];
    *reinterpret_cast<float4*>(&w[P * PADW + 4 * c]) = v;
  }
  __syncthreads();

  const int wave = threadIdx.x >> 6;
  const int lane = threadIdx.x & 63;
  const int g    = blockIdx.x * 4 + wave;         // 0..2047, 8 rows per wave

  float bb[CD];
#pragma unroll
  for (int d = 0; d < CD; ++d) bb[d] = bin[d];

  for (int it = 0; it < 4; ++it) {                // 2 rows per iteration
    const int row0 = g * 8 + it * 2;
    const float4* xr0 = reinterpret_cast<const float4*>(x + (size_t)row0 * DIMX);
    const float4* xr1 = reinterpret_cast<const float4*>(x + (size_t)(row0 + 1) * DIMX);
    float a0[CD], a1[CD];
#pragma unroll
    for (int d = 0; d < CD; ++d) { a0[d] = 0.f; a1[d] = 0.f; }

#pragma unroll
    for (int k = 0; k < 4; ++k) {
      const int P = lane + 64 * k;
      float4 xv0 = xr0[P];
      float4 xv1 = xr1[P];
      const float4* wf = reinterpret_cast<const float4*>(&w[P * PADW]);
      float4 wq[12];
#pragma unroll
      for (int c = 0; c < 12; ++c) wq[c] = wf[c];
      const float* wfl = reinterpret_cast<const float*>(wq);
      float xe0[4] = {xv0.x, xv0.y, xv0.z, xv0.w};
      float xe1[4] = {xv1.x, xv1.y, xv1.z, xv1.w};
#pragma unroll
      for (int e = 0; e < 4; ++e)
#pragma unroll
        for (int d = 0; d < CD; ++d) {
          const float wv = wfl[e * CD + d];
          a0[d] = fmaf(xe0[e], wv, a0[d]);
          a1[d] = fmaf(xe1[e], wv, a1[d]);
        }
    }
#pragma unroll
    for (int ofs = 1; ofs < 64; ofs <<= 1)
#pragma unroll
      for (int d = 0; d < CD; ++d) {
        a0[d] += __shfl_xor(a0[d], ofs, 64);
        a1[d] += __shfl_xor(a1[d], ofs, 64);
      }

    if (lane == 0) {
      int i0 = 0, i1 = 0;
#pragma unroll
      for (int d = 0; d < CD; ++d) {
        const float h0 = a0[d] + bb[d];
        const float h1 = a1[d] + bb[d];
        h[(size_t)row0 * CD + d]       = h0;
        h[(size_t)(row0 + 1) * CD + d] = h1;
        i0 |= (h0 > 0.f) ? (1 << d) : 0;
        i1 |= (h1 > 0.f) ? (1 << d) : 0;
      }
      oidx[row0]     = (float)i0;
      oidx[row0 + 1] = (float)i1;
    }
  }
}

// ---------- Kernel B: out = sign(h) @ W_out + b_out (signs from oidx) ----------
__global__ __launch_bounds__(256, 2) void k_out(
    const float* __restrict__ Wout, const float* __restrict__ bout,
    const float* __restrict__ oidx, float* __restrict__ out, int rows_pb)
{
  const int t = threadIdx.x;
  float wreg[CD][4];
#pragma unroll
  for (int d = 0; d < CD; ++d) {
    float4 v = *reinterpret_cast<const float4*>(Wout + d * DIMX + 4 * t);
    wreg[d][0] = v.x; wreg[d][1] = v.y; wreg[d][2] = v.z; wreg[d][3] = v.w;
  }
  float4 b4 = *reinterpret_cast<const float4*>(bout + 4 * t);

  const int row0 = blockIdx.x * rows_pb;
  for (int i = 0; i < rows_pb; ++i) {
    const int row = row0 + i;
    const int idx = (int)oidx[row];               // block-uniform scalar load
    float o0 = b4.x, o1 = b4.y, o2 = b4.z, o3 = b4.w;
#pragma unroll
    for (int d = 0; d < CD; ++d) {
      const float s = ((idx >> d) & 1) ? 1.f : -1.f;
      o0 = fmaf(s, wreg[d][0], o0);
      o1 = fmaf(s, wreg[d][1], o1);
      o2 = fmaf(s, wreg[d][2], o2);
      o3 = fmaf(s, wreg[d][3], o3);
    }
    reinterpret_cast<float4*>(out + (size_t)row * DIMX)[t] = make_float4(o0, o1, o2, o3);
  }
}

// ---------- Kernel C: entropy + commit + factorized histogram ----------
// Round-5 lesson: this toolchain never allocates >~56 VGPRs (spills instead),
// so k_ent must carry NO per-thread accumulator state. Per row we compute the
// factorized tree (named scalars, ~35 transient regs) and accumulate E*D
// products straight into the block's LDS histogram with ds_add_f32 (no-return
// atomic: no register held, no waitcnt dependency). Addresses lane*4 + m*256
// are 2-way bank-aliased = conflict-free.
__global__ __launch_bounds__(256) void k_ent(
    const float* __restrict__ h, float* __restrict__ hist_part,
    float* __restrict__ pse, float* __restrict__ com, int rpw)
{
  __shared__ float lh[KCB];                       // 16 KiB block histogram
  const int lane = threadIdx.x & 63;
  const int wid  = threadIdx.x >> 6;

  for (int i = threadIdx.x; i < KCB; i += 256) lh[i] = 0.f;
  __syncthreads();

  float pse_acc = 0.f, com_acc = 0.f;
  float* lp = &lh[lane];

  const int r0 = (blockIdx.x * 4 + wid) * rpw;
  for (int i = 0; i < rpw; ++i) {
    const int row = r0 + i;
    float qv = 0.f;
    if (lane < CD) {
      const float hv = h[(size_t)row * CD + lane];
      const float ax  = fabsf(40.f * hv);
      const float e2  = __expf(-ax);
      const float s1  = 1.f + e2;
      const float inv = 1.f / s1;
      qv = (hv > 0.f) ? inv : e2 * inv;           // sigmoid(40 h)
      pse_acc += __logf(s1) + ax * e2 * inv;      // per-dim entropy term
      const float dd = fabsf(hv) - 1.f;
      com_acc += dd * dd;
    }
    const float q0  = __shfl(qv, 0, 64),  q1  = __shfl(qv, 1, 64);
    const float q2  = __shfl(qv, 2, 64),  q3  = __shfl(qv, 3, 64);
    const float q4  = __shfl(qv, 4, 64),  q5  = __shfl(qv, 5, 64);
    const float q6  = __shfl(qv, 6, 64),  q7  = __shfl(qv, 7, 64);
    const float q8  = __shfl(qv, 8, 64),  q9  = __shfl(qv, 9, 64);
    const float q10 = __shfl(qv, 10, 64), q11 = __shfl(qv, 11, 64);

    float A = ((lane >> 0) & 1) ? q0 : 1.f - q0;
    A      *= ((lane >> 1) & 1) ? q1 : 1.f - q1;
    A      *= ((lane >> 2) & 1) ? q2 : 1.f - q2;
    A      *= ((lane >> 3) & 1) ? q3 : 1.f - q3;
    A      *= ((lane >> 4) & 1) ? q4 : 1.f - q4;
    A      *= ((lane >> 5) & 1) ? q5 : 1.f - q5;

    const float t6 = 1.f - q6, t7 = 1.f - q7, t8 = 1.f - q8;
    const float u0 = t6 * t7, u1 = q6 * t7, u2 = t6 * q7, u3 = q6 * q7;
    const float E0 = A * (u0 * t8), E1 = A * (u1 * t8), E2 = A * (u2 * t8), E3 = A * (u3 * t8);
    const float E4 = A * (u0 * q8), E5 = A * (u1 * q8), E6 = A * (u2 * q8), E7 = A * (u3 * q8);
    const float t9 = 1.f - q9, t10 = 1.f - q10, t11 = 1.f - q11;
    const float v0 = t9 * t10, v1 = q9 * t10, v2 = t9 * q10, v3 = q9 * q10;
    const float D0 = v0 * t11, D1 = v1 * t11, D2 = v2 * t11, D3 = v3 * t11;
    const float D4 = v0 * q11, D5 = v1 * q11, D6 = v2 * q11, D7 = v3 * q11;

    atomicAdd(lp +  0*64, E0*D0); atomicAdd(lp +  1*64, E1*D0); atomicAdd(lp +  2*64, E2*D0); atomicAdd(lp +  3*64, E3*D0);
    atomicAdd(lp +  4*64, E4*D0); atomicAdd(lp +  5*64, E5*D0); atomicAdd(lp +  6*64, E6*D0); atomicAdd(lp +  7*64, E7*D0);
    atomicAdd(lp +  8*64, E0*D1); atomicAdd(lp +  9*64, E1*D1); atomicAdd(lp + 10*64, E2*D1); atomicAdd(lp + 11*64, E3*D1);
    atomicAdd(lp + 12*64, E4*D1); atomicAdd(lp + 13*64, E5*D1); atomicAdd(lp + 14*64, E6*D1); atomicAdd(lp + 15*64, E7*D1);
    atomicAdd(lp + 16*64, E0*D2); atomicAdd(lp + 17*64, E1*D2); atomicAdd(lp + 18*64, E2*D2); atomicAdd(lp + 19*64, E3*D2);
    atomicAdd(lp + 20*64, E4*D2); atomicAdd(lp + 21*64, E5*D2); atomicAdd(lp + 22*64, E6*D2); atomicAdd(lp + 23*64, E7*D2);
    atomicAdd(lp + 24*64, E0*D3); atomicAdd(lp + 25*64, E1*D3); atomicAdd(lp + 26*64, E2*D3); atomicAdd(lp + 27*64, E3*D3);
    atomicAdd(lp + 28*64, E4*D3); atomicAdd(lp + 29*64, E5*D3); atomicAdd(lp + 30*64, E6*D3); atomicAdd(lp + 31*64, E7*D3);
    atomicAdd(lp + 32*64, E0*D4); atomicAdd(lp + 33*64, E1*D4); atomicAdd(lp + 34*64, E2*D4); atomicAdd(lp + 35*64, E3*D4);
    atomicAdd(lp + 36*64, E4*D4); atomicAdd(lp + 37*64, E5*D4); atomicAdd(lp + 38*64, E6*D4); atomicAdd(lp + 39*64, E7*D4);
    atomicAdd(lp + 40*64, E0*D5); atomicAdd(lp + 41*64, E1*D5); atomicAdd(lp + 42*64, E2*D5); atomicAdd(lp + 43*64, E3*D5);
    atomicAdd(lp + 44*64, E4*D5); atomicAdd(lp + 45*64, E5*D5); atomicAdd(lp + 46*64, E6*D5); atomicAdd(lp + 47*64, E7*D5);
    atomicAdd(lp + 48*64, E0*D6); atomicAdd(lp + 49*64, E1*D6); atomicAdd(lp + 50*64, E2*D6); atomicAdd(lp + 51*64, E3*D6);
    atomicAdd(lp + 52*64, E4*D6); atomicAdd(lp + 53*64, E5*D6); atomicAdd(lp + 54*64, E6*D6); atomicAdd(lp + 55*64, E7*D6);
    atomicAdd(lp + 56*64, E0*D7); atomicAdd(lp + 57*64, E1*D7); atomicAdd(lp + 58*64, E2*D7); atomicAdd(lp + 59*64, E3*D7);
    atomicAdd(lp + 60*64, E4*D7); atomicAdd(lp + 61*64, E5*D7); atomicAdd(lp + 62*64, E6*D7); atomicAdd(lp + 63*64, E7*D7);
  }
  __syncthreads();

  // one coalesced 16 KiB store per block
  float4* hp = reinterpret_cast<float4*>(hist_part + (size_t)blockIdx.x * KCB);
  const float4* ls = reinterpret_cast<const float4*>(lh);
  for (int i = threadIdx.x; i < KCB / 4; i += 256) hp[i] = ls[i];

#pragma unroll
  for (int ofs = 1; ofs < 64; ofs <<= 1) {
    pse_acc += __shfl_xor(pse_acc, ofs, 64);
    com_acc += __shfl_xor(com_acc, ofs, 64);
  }
  if (lane == 0) { atomicAdd(pse, pse_acc); atomicAdd(com, com_acc); }
}

// ---------- Kernel D1: partial slab reduction (chunked) ----------
__global__ __launch_bounds__(256) void k_hr1(
    const float* __restrict__ hist_part, float* __restrict__ part2,
    int nslab)
{
  const int j     = (blockIdx.x & 15) * 256 + threadIdx.x;
  const int chunk = blockIdx.x >> 4;              // 0..15
  const int per   = nslab >> 4;
  const int b0    = chunk * per;
  float acc = 0.f;
#pragma unroll 4
  for (int b = 0; b < per; ++b)
    acc += hist_part[(size_t)(b0 + b) * KCB + j];
  part2[(size_t)chunk * KCB + j] = acc;
}

// ---------- Kernel D2: final codebook entropy ----------
__global__ __launch_bounds__(256) void k_hr2(
    const float* __restrict__ part2, float* __restrict__ cbe)
{
  const int j = blockIdx.x * 256 + threadIdx.x;
  float acc = 0.f;
#pragma unroll
  for (int c = 0; c < 16; ++c) acc += part2[(size_t)c * KCB + j];
  const float a = acc * (1.f / 16384.f);
  float term = -a * __logf(a + 1e-10f);
#pragma unroll
  for (int ofs = 1; ofs < 64; ofs <<= 1) term += __shfl_xor(term, ofs, 64);
  __shared__ float sw[4];
  if ((threadIdx.x & 63) == 0) sw[threadIdx.x >> 6] = term;
  __syncthreads();
  if (threadIdx.x == 0) atomicAdd(cbe, sw[0] + sw[1] + sw[2] + sw[3]);
}

// ---------- Kernel E: combine scalars ----------
__global__ void k_aux(const float* __restrict__ pse, const float* __restrict__ com,
                      const float* __restrict__ cbe, float* __restrict__ aux)
{
  aux[0] = pse[0] * (1.f / 16384.f) - cbe[0] + com[0] * (1.f / 196608.f);
}

extern "C" void kernel_launch(void* const* d_in, const int* in_sizes, int n_in,
                              void* d_out, int out_size, void* d_ws, size_t ws_size,
                              hipStream_t stream)
{
  const float* x    = (const float*)d_in[0];
  const float* Win  = (const float*)d_in[1];
  const float* bin  = (const float*)d_in[2];
  const float* Wout = (const float*)d_in[3];
  const float* bout = (const float*)d_in[4];

  float* out  = (float*)d_out;                       // [16384 x 1024]
  float* oidx = out + (size_t)M_ROWS * DIMX;         // [16384]
  float* aux  = oidx + M_ROWS;                       // [1]

  float* ws        = (float*)d_ws;
  float* h         = ws;                             // 196608 floats
  float* scal      = ws + (size_t)M_ROWS * CD;       // pse, com, cbe (pad 16)
  float* pse       = scal;
  float* com       = scal + 1;
  float* cbe       = scal + 2;
  float* part2     = scal + 16;                      // 16 * 4096 floats
  float* hist_part = part2 + 16 * KCB;               // nblk * 4096 floats

  // one histogram slab per BLOCK (4 waves combined in LDS via ds_add_f32)
  int nblk = 512;
  while (nblk > 64 &&
         ((size_t)M_ROWS * CD + 16 + 16 * KCB + (size_t)nblk * KCB) * 4 > ws_size)
    nblk >>= 1;
  const int rpw = M_ROWS / (nblk * 4);               // rows per wave

  hipMemsetAsync(scal, 0, 3 * sizeof(float), stream);
  k_hproj<<<512, 256, 0, stream>>>(x, Win, bin, h, oidx);
  k_ent  <<<nblk, 256, 0, stream>>>(h, hist_part, pse, com, rpw);   // h still L2-warm
  k_out  <<<512, 256, 0, stream>>>(Wout, bout, oidx, out, M_ROWS / 512);
  k_hr1  <<<256, 256, 0, stream>>>(hist_part, part2, nblk);
  k_hr2  <<<KCB / 256, 256, 0, stream>>>(part2, cbe);
  k_aux  <<<1, 1, 0, stream>>>(pse, com, cbe, aux);
}

// Round 7
// 105.157 us; speedup vs baseline: 4.0425x; 4.0425x over previous
//
#include <hip/hip_runtime.h>

#define M_ROWS 16384
#define DIMX   1024
#define CD     12
#define KCB    4096
#define PADW   60   // padded dwords per float4-position fragment (48 data + 12 pad)

// ---------- Kernel A: h = x @ W_in + b_in ; writes h and oidx ----------
// Arithmetic (FMA order k,e,d; butterfly ofs 1..32; +bin at end) is bit-identical
// to the round-1/2 version that produced exact index match.
__global__ __launch_bounds__(256, 2) void k_hproj(
    const float* __restrict__ x, const float* __restrict__ Win,
    const float* __restrict__ bin, float* __restrict__ h, float* __restrict__ oidx)
{
  __shared__ __align__(16) float w[256 * PADW];   // 60 KB, conflict-free stride
  for (int f = threadIdx.x; f < 256 * 12; f += 256) {
    const int P = f / 12, c = f % 12;
    float4 v = reinterpret_cast<const float4*>(Win)[f];
    *reinterpret_cast<float4*>(&w[P * PADW + 4 * c]) = v;
  }
  __syncthreads();

  const int wave = threadIdx.x >> 6;
  const int lane = threadIdx.x & 63;
  const int g    = blockIdx.x * 4 + wave;         // 0..2047, 8 rows per wave

  float bb[CD];
#pragma unroll
  for (int d = 0; d < CD; ++d) bb[d] = bin[d];

  for (int it = 0; it < 4; ++it) {                // 2 rows per iteration
    const int row0 = g * 8 + it * 2;
    const float4* xr0 = reinterpret_cast<const float4*>(x + (size_t)row0 * DIMX);
    const float4* xr1 = reinterpret_cast<const float4*>(x + (size_t)(row0 + 1) * DIMX);
    float a0[CD], a1[CD];
#pragma unroll
    for (int d = 0; d < CD; ++d) { a0[d] = 0.f; a1[d] = 0.f; }

#pragma unroll
    for (int k = 0; k < 4; ++k) {
      const int P = lane + 64 * k;
      float4 xv0 = xr0[P];
      float4 xv1 = xr1[P];
      const float4* wf = reinterpret_cast<const float4*>(&w[P * PADW]);
      float4 wq[12];
#pragma unroll
      for (int c = 0; c < 12; ++c) wq[c] = wf[c];
      const float* wfl = reinterpret_cast<const float*>(wq);
      float xe0[4] = {xv0.x, xv0.y, xv0.z, xv0.w};
      float xe1[4] = {xv1.x, xv1.y, xv1.z, xv1.w};
#pragma unroll
      for (int e = 0; e < 4; ++e)
#pragma unroll
        for (int d = 0; d < CD; ++d) {
          const float wv = wfl[e * CD + d];
          a0[d] = fmaf(xe0[e], wv, a0[d]);
          a1[d] = fmaf(xe1[e], wv, a1[d]);
        }
    }
#pragma unroll
    for (int ofs = 1; ofs < 64; ofs <<= 1)
#pragma unroll
      for (int d = 0; d < CD; ++d) {
        a0[d] += __shfl_xor(a0[d], ofs, 64);
        a1[d] += __shfl_xor(a1[d], ofs, 64);
      }

    if (lane == 0) {
      int i0 = 0, i1 = 0;
#pragma unroll
      for (int d = 0; d < CD; ++d) {
        const float h0 = a0[d] + bb[d];
        const float h1 = a1[d] + bb[d];
        h[(size_t)row0 * CD + d]       = h0;
        h[(size_t)(row0 + 1) * CD + d] = h1;
        i0 |= (h0 > 0.f) ? (1 << d) : 0;
        i1 |= (h1 > 0.f) ? (1 << d) : 0;
      }
      oidx[row0]     = (float)i0;
      oidx[row0 + 1] = (float)i1;
    }
  }
}

// ---------- Kernel B: out = sign(h) @ W_out + b_out (signs from oidx) ----------
__global__ __launch_bounds__(256, 2) void k_out(
    const float* __restrict__ Wout, const float* __restrict__ bout,
    const float* __restrict__ oidx, float* __restrict__ out, int rows_pb)
{
  const int t = threadIdx.x;
  float wreg[CD][4];
#pragma unroll
  for (int d = 0; d < CD; ++d) {
    float4 v = *reinterpret_cast<const float4*>(Wout + d * DIMX + 4 * t);
    wreg[d][0] = v.x; wreg[d][1] = v.y; wreg[d][2] = v.z; wreg[d][3] = v.w;
  }
  float4 b4 = *reinterpret_cast<const float4*>(bout + 4 * t);

  const int row0 = blockIdx.x * rows_pb;
  for (int i = 0; i < rows_pb; ++i) {
    const int row = row0 + i;
    const int idx = (int)oidx[row];               // block-uniform scalar load
    float o0 = b4.x, o1 = b4.y, o2 = b4.z, o3 = b4.w;
#pragma unroll
    for (int d = 0; d < CD; ++d) {
      const float s = ((idx >> d) & 1) ? 1.f : -1.f;
      o0 = fmaf(s, wreg[d][0], o0);
      o1 = fmaf(s, wreg[d][1], o1);
      o2 = fmaf(s, wreg[d][2], o2);
      o3 = fmaf(s, wreg[d][3], o3);
    }
    reinterpret_cast<float4*>(out + (size_t)row * DIMX)[t] = make_float4(o0, o1, o2, o3);
  }
}

// ---------- Kernel C: entropy + commit + factorized histogram ----------
// Round-6 lesson: the RA targets 8 waves/SIMD (<=~56 VGPR) and spills anything
// bigger, so the kernel is DESIGNED to fit: each wave owns only a 16-m quarter
// of the histogram (16 named accumulators; peak live ~44 regs). All 4 waves of
// a block process the same rows (redundant q tree, ~36 instr/row) and write
// disjoint slices of the block's slab with plain coalesced stores. No LDS, no
// atomics in the hot path.
__global__ __launch_bounds__(256) void k_ent(
    const float* __restrict__ h, float* __restrict__ hist_part,
    float* __restrict__ pse, float* __restrict__ com, int rpw)
{
  const int lane = threadIdx.x & 63;
  const int wid  = threadIdx.x >> 6;    // quarter: m in [wid*16, wid*16+16)
  const int bid  = blockIdx.x;

  float b0=0.f,b1=0.f,b2=0.f,b3=0.f,b4=0.f,b5=0.f,b6=0.f,b7=0.f,
        b8=0.f,b9=0.f,b10=0.f,b11=0.f,b12=0.f,b13=0.f,b14=0.f,b15=0.f;
  float pse_acc = 0.f, com_acc = 0.f;

  const int r0 = bid * rpw;
  for (int i = 0; i < rpw; ++i) {
    const int row = r0 + i;
    float qv = 0.f;
    if (lane < CD) {
      const float hv = h[(size_t)row * CD + lane];
      const float ax  = fabsf(40.f * hv);
      const float e2  = __expf(-ax);
      const float s1  = 1.f + e2;
      const float inv = 1.f / s1;
      qv = (hv > 0.f) ? inv : e2 * inv;           // sigmoid(40 h)
      pse_acc += __logf(s1) + ax * e2 * inv;      // per-dim entropy term
      const float dd = fabsf(hv) - 1.f;
      com_acc += dd * dd;
    }
    const float q0  = __shfl(qv, 0, 64),  q1  = __shfl(qv, 1, 64);
    const float q2  = __shfl(qv, 2, 64),  q3  = __shfl(qv, 3, 64);
    const float q4  = __shfl(qv, 4, 64),  q5  = __shfl(qv, 5, 64);
    const float q6  = __shfl(qv, 6, 64),  q7  = __shfl(qv, 7, 64);
    const float q8  = __shfl(qv, 8, 64),  q9  = __shfl(qv, 9, 64);
    const float q10 = __shfl(qv, 10, 64), q11 = __shfl(qv, 11, 64);

    // A over the low 6 bits (lane-dependent)
    float A = ((lane >> 0) & 1) ? q0 : 1.f - q0;
    A      *= ((lane >> 1) & 1) ? q1 : 1.f - q1;
    A      *= ((lane >> 2) & 1) ? q2 : 1.f - q2;
    A      *= ((lane >> 3) & 1) ? q3 : 1.f - q3;
    A      *= ((lane >> 4) & 1) ? q4 : 1.f - q4;
    A      *= ((lane >> 5) & 1) ? q5 : 1.f - q5;

    // E = A * C over dims 6..8 (shared by all quarters)
    const float t6 = 1.f - q6, t7 = 1.f - q7, t8 = 1.f - q8;
    const float u0 = t6 * t7, u1 = q6 * t7, u2 = t6 * q7, u3 = q6 * q7;
    const float E0 = A * (u0 * t8), E1 = A * (u1 * t8), E2 = A * (u2 * t8), E3 = A * (u3 * t8);
    const float E4 = A * (u0 * q8), E5 = A * (u1 * q8), E6 = A * (u2 * q8), E7 = A * (u3 * q8);

    // this wave's two D values: m>>3 = wid*2 {+1}; D_j = v[j&3] * (j>=4 ? q11 : t11)
    const float t9 = 1.f - q9, t10 = 1.f - q10;
    const float vl = (wid & 1) ? ((1.f - q9) * q10) : (t9 * t10);   // v2 : v0
    const float vh = (wid & 1) ? (q9 * q10)          : (q9 * t10);  // v3 : v1
    const float w11 = (wid & 2) ? q11 : (1.f - q11);
    const float Dlo = vl * w11;
    const float Dhi = vh * w11;

    b0  = fmaf(E0, Dlo, b0);  b1  = fmaf(E1, Dlo, b1);  b2  = fmaf(E2, Dlo, b2);  b3  = fmaf(E3, Dlo, b3);
    b4  = fmaf(E4, Dlo, b4);  b5  = fmaf(E5, Dlo, b5);  b6  = fmaf(E6, Dlo, b6);  b7  = fmaf(E7, Dlo, b7);
    b8  = fmaf(E0, Dhi, b8);  b9  = fmaf(E1, Dhi, b9);  b10 = fmaf(E2, Dhi, b10); b11 = fmaf(E3, Dhi, b11);
    b12 = fmaf(E4, Dhi, b12); b13 = fmaf(E5, Dhi, b13); b14 = fmaf(E6, Dhi, b14); b15 = fmaf(E7, Dhi, b15);
  }

  // write this wave's disjoint 16x64 slice of the block's slab (coalesced)
  float* hp = hist_part + (size_t)bid * KCB + (size_t)wid * 1024 + lane;
  hp[ 0*64] = b0;  hp[ 1*64] = b1;  hp[ 2*64] = b2;  hp[ 3*64] = b3;
  hp[ 4*64] = b4;  hp[ 5*64] = b5;  hp[ 6*64] = b6;  hp[ 7*64] = b7;
  hp[ 8*64] = b8;  hp[ 9*64] = b9;  hp[10*64] = b10; hp[11*64] = b11;
  hp[12*64] = b12; hp[13*64] = b13; hp[14*64] = b14; hp[15*64] = b15;

  // pse/com: identical in all 4 waves (same rows) -> commit from wave 0 only
  if (wid == 0) {
#pragma unroll
    for (int ofs = 1; ofs < 64; ofs <<= 1) {
      pse_acc += __shfl_xor(pse_acc, ofs, 64);
      com_acc += __shfl_xor(com_acc, ofs, 64);
    }
    if (lane == 0) { atomicAdd(pse, pse_acc); atomicAdd(com, com_acc); }
  }
}

// ---------- Kernel D1: partial slab reduction (chunked) ----------
__global__ __launch_bounds__(256) void k_hr1(
    const float* __restrict__ hist_part, float* __restrict__ part2,
    int nslab)
{
  const int j     = (blockIdx.x & 15) * 256 + threadIdx.x;
  const int chunk = blockIdx.x >> 4;              // 0..15
  const int per   = nslab >> 4;
  const int b0    = chunk * per;
  float acc = 0.f;
#pragma unroll 4
  for (int b = 0; b < per; ++b)
    acc += hist_part[(size_t)(b0 + b) * KCB + j];
  part2[(size_t)chunk * KCB + j] = acc;
}

// ---------- Kernel D2: final codebook entropy ----------
__global__ __launch_bounds__(256) void k_hr2(
    const float* __restrict__ part2, float* __restrict__ cbe)
{
  const int j = blockIdx.x * 256 + threadIdx.x;
  float acc = 0.f;
#pragma unroll
  for (int c = 0; c < 16; ++c) acc += part2[(size_t)c * KCB + j];
  const float a = acc * (1.f / 16384.f);
  float term = -a * __logf(a + 1e-10f);
#pragma unroll
  for (int ofs = 1; ofs < 64; ofs <<= 1) term += __shfl_xor(term, ofs, 64);
  __shared__ float sw[4];
  if ((threadIdx.x & 63) == 0) sw[threadIdx.x >> 6] = term;
  __syncthreads();
  if (threadIdx.x == 0) atomicAdd(cbe, sw[0] + sw[1] + sw[2] + sw[3]);
}

// ---------- Kernel E: combine scalars ----------
__global__ void k_aux(const float* __restrict__ pse, const float* __restrict__ com,
                      const float* __restrict__ cbe, float* __restrict__ aux)
{
  aux[0] = pse[0] * (1.f / 16384.f) - cbe[0] + com[0] * (1.f / 196608.f);
}

extern "C" void kernel_launch(void* const* d_in, const int* in_sizes, int n_in,
                              void* d_out, int out_size, void* d_ws, size_t ws_size,
                              hipStream_t stream)
{
  const float* x    = (const float*)d_in[0];
  const float* Win  = (const float*)d_in[1];
  const float* bin  = (const float*)d_in[2];
  const float* Wout = (const float*)d_in[3];
  const float* bout = (const float*)d_in[4];

  float* out  = (float*)d_out;                       // [16384 x 1024]
  float* oidx = out + (size_t)M_ROWS * DIMX;         // [16384]
  float* aux  = oidx + M_ROWS;                       // [1]

  float* ws        = (float*)d_ws;
  float* h         = ws;                             // 196608 floats
  float* scal      = ws + (size_t)M_ROWS * CD;       // pse, com, cbe (pad 16)
  float* pse       = scal;
  float* com       = scal + 1;
  float* cbe       = scal + 2;
  float* part2     = scal + 16;                      // 16 * 4096 floats
  float* hist_part = part2 + 16 * KCB;               // nblk * 4096 floats

  // one histogram slab per BLOCK (4 waves write disjoint quarters)
  int nblk = 1024;
  while (nblk > 64 &&
         ((size_t)M_ROWS * CD + 16 + 16 * KCB + (size_t)nblk * KCB) * 4 > ws_size)
    nblk >>= 1;
  const int rpw = M_ROWS / nblk;                     // rows per block (all 4 waves)

  hipMemsetAsync(scal, 0, 3 * sizeof(float), stream);
  k_hproj<<<512, 256, 0, stream>>>(x, Win, bin, h, oidx);
  k_ent  <<<nblk, 256, 0, stream>>>(h, hist_part, pse, com, rpw);   // h still L2-warm
  k_out  <<<512, 256, 0, stream>>>(Wout, bout, oidx, out, M_ROWS / 512);
  k_hr1  <<<256, 256, 0, stream>>>(hist_part, part2, nblk);
  k_hr2  <<<KCB / 256, 256, 0, stream>>>(part2, cbe);
  k_aux  <<<1, 1, 0, stream>>>(pse, com, cbe, aux);
}

// Round 8
// 100.513 us; speedup vs baseline: 4.2293x; 1.0462x over previous
//
#include <hip/hip_runtime.h>

#define M_ROWS 16384
#define DIMX   1024
#define CD     12
#define KCB    4096
#define PADW   60   // padded dwords per float4-position fragment (48 data + 12 pad)

// ---------- Kernel A: h = x @ W_in + b_in ; writes h and oidx ----------
// Arithmetic (FMA order k,e,d; butterfly ofs 1..32; +bin at end) is bit-identical
// to the round-1/2 version that produced exact index match.
// Round-7: also zeroes the 3 scalar accumulators (pse/com/cbe) from one thread —
// replaces a hipMemsetAsync that cost ~40 us of stream time per call.
__global__ __launch_bounds__(256, 2) void k_hproj(
    const float* __restrict__ x, const float* __restrict__ Win,
    const float* __restrict__ bin, float* __restrict__ h, float* __restrict__ oidx,
    float* __restrict__ scal)
{
  if (blockIdx.x == 0 && threadIdx.x == 0) {
    scal[0] = 0.f; scal[1] = 0.f; scal[2] = 0.f;   // pse, com, cbe
  }

  __shared__ __align__(16) float w[256 * PADW];   // 60 KB, conflict-free stride
  for (int f = threadIdx.x; f < 256 * 12; f += 256) {
    const int P = f / 12, c = f % 12;
    float4 v = reinterpret_cast<const float4*>(Win)[f];
    *reinterpret_cast<float4*>(&w[P * PADW + 4 * c]) = v;
  }
  __syncthreads();

  const int wave = threadIdx.x >> 6;
  const int lane = threadIdx.x & 63;
  const int g    = blockIdx.x * 4 + wave;         // 0..2047, 8 rows per wave

  float bb[CD];
#pragma unroll
  for (int d = 0; d < CD; ++d) bb[d] = bin[d];

  for (int it = 0; it < 4; ++it) {                // 2 rows per iteration
    const int row0 = g * 8 + it * 2;
    const float4* xr0 = reinterpret_cast<const float4*>(x + (size_t)row0 * DIMX);
    const float4* xr1 = reinterpret_cast<const float4*>(x + (size_t)(row0 + 1) * DIMX);
    float a0[CD], a1[CD];
#pragma unroll
    for (int d = 0; d < CD; ++d) { a0[d] = 0.f; a1[d] = 0.f; }

#pragma unroll
    for (int k = 0; k < 4; ++k) {
      const int P = lane + 64 * k;
      float4 xv0 = xr0[P];
      float4 xv1 = xr1[P];
      const float4* wf = reinterpret_cast<const float4*>(&w[P * PADW]);
      float4 wq[12];
#pragma unroll
      for (int c = 0; c < 12; ++c) wq[c] = wf[c];
      const float* wfl = reinterpret_cast<const float*>(wq);
      float xe0[4] = {xv0.x, xv0.y, xv0.z, xv0.w};
      float xe1[4] = {xv1.x, xv1.y, xv1.z, xv1.w};
#pragma unroll
      for (int e = 0; e < 4; ++e)
#pragma unroll
        for (int d = 0; d < CD; ++d) {
          const float wv = wfl[e * CD + d];
          a0[d] = fmaf(xe0[e], wv, a0[d]);
          a1[d] = fmaf(xe1[e], wv, a1[d]);
        }
    }
#pragma unroll
    for (int ofs = 1; ofs < 64; ofs <<= 1)
#pragma unroll
      for (int d = 0; d < CD; ++d) {
        a0[d] += __shfl_xor(a0[d], ofs, 64);
        a1[d] += __shfl_xor(a1[d], ofs, 64);
      }

    if (lane == 0) {
      int i0 = 0, i1 = 0;
#pragma unroll
      for (int d = 0; d < CD; ++d) {
        const float h0 = a0[d] + bb[d];
        const float h1 = a1[d] + bb[d];
        h[(size_t)row0 * CD + d]       = h0;
        h[(size_t)(row0 + 1) * CD + d] = h1;
        i0 |= (h0 > 0.f) ? (1 << d) : 0;
        i1 |= (h1 > 0.f) ? (1 << d) : 0;
      }
      oidx[row0]     = (float)i0;
      oidx[row0 + 1] = (float)i1;
    }
  }
}

// ---------- Kernel B: out = sign(h) @ W_out + b_out (signs from oidx) ----------
__global__ __launch_bounds__(256, 2) void k_out(
    const float* __restrict__ Wout, const float* __restrict__ bout,
    const float* __restrict__ oidx, float* __restrict__ out, int rows_pb)
{
  const int t = threadIdx.x;
  float wreg[CD][4];
#pragma unroll
  for (int d = 0; d < CD; ++d) {
    float4 v = *reinterpret_cast<const float4*>(Wout + d * DIMX + 4 * t);
    wreg[d][0] = v.x; wreg[d][1] = v.y; wreg[d][2] = v.z; wreg[d][3] = v.w;
  }
  float4 b4 = *reinterpret_cast<const float4*>(bout + 4 * t);

  const int row0 = blockIdx.x * rows_pb;
  for (int i = 0; i < rows_pb; ++i) {
    const int row = row0 + i;
    const int idx = (int)oidx[row];               // block-uniform scalar load
    float o0 = b4.x, o1 = b4.y, o2 = b4.z, o3 = b4.w;
#pragma unroll
    for (int d = 0; d < CD; ++d) {
      const float s = ((idx >> d) & 1) ? 1.f : -1.f;
      o0 = fmaf(s, wreg[d][0], o0);
      o1 = fmaf(s, wreg[d][1], o1);
      o2 = fmaf(s, wreg[d][2], o2);
      o3 = fmaf(s, wreg[d][3], o3);
    }
    reinterpret_cast<float4*>(out + (size_t)row * DIMX)[t] = make_float4(o0, o1, o2, o3);
  }
}

// ---------- Kernel C: entropy + commit + factorized histogram ----------
// Each wave owns a 16-m quarter of the histogram (16 named accumulators; peak
// live ~44 regs, fits the RA's 8-wave budget). All 4 waves process the same
// rows; disjoint slices written with plain coalesced stores. No LDS/atomics.
__global__ __launch_bounds__(256) void k_ent(
    const float* __restrict__ h, float* __restrict__ hist_part,
    float* __restrict__ pse, float* __restrict__ com, int rpw)
{
  const int lane = threadIdx.x & 63;
  const int wid  = threadIdx.x >> 6;    // quarter: m in [wid*16, wid*16+16)
  const int bid  = blockIdx.x;

  float b0=0.f,b1=0.f,b2=0.f,b3=0.f,b4=0.f,b5=0.f,b6=0.f,b7=0.f,
        b8=0.f,b9=0.f,b10=0.f,b11=0.f,b12=0.f,b13=0.f,b14=0.f,b15=0.f;
  float pse_acc = 0.f, com_acc = 0.f;

  const int r0 = bid * rpw;
  for (int i = 0; i < rpw; ++i) {
    const int row = r0 + i;
    float qv = 0.f;
    if (lane < CD) {
      const float hv = h[(size_t)row * CD + lane];
      const float ax  = fabsf(40.f * hv);
      const float e2  = __expf(-ax);
      const float s1  = 1.f + e2;
      const float inv = 1.f / s1;
      qv = (hv > 0.f) ? inv : e2 * inv;           // sigmoid(40 h)
      pse_acc += __logf(s1) + ax * e2 * inv;      // per-dim entropy term
      const float dd = fabsf(hv) - 1.f;
      com_acc += dd * dd;
    }
    const float q0  = __shfl(qv, 0, 64),  q1  = __shfl(qv, 1, 64);
    const float q2  = __shfl(qv, 2, 64),  q3  = __shfl(qv, 3, 64);
    const float q4  = __shfl(qv, 4, 64),  q5  = __shfl(qv, 5, 64);
    const float q6  = __shfl(qv, 6, 64),  q7  = __shfl(qv, 7, 64);
    const float q8  = __shfl(qv, 8, 64),  q9  = __shfl(qv, 9, 64);
    const float q10 = __shfl(qv, 10, 64), q11 = __shfl(qv, 11, 64);

    // A over the low 6 bits (lane-dependent)
    float A = ((lane >> 0) & 1) ? q0 : 1.f - q0;
    A      *= ((lane >> 1) & 1) ? q1 : 1.f - q1;
    A      *= ((lane >> 2) & 1) ? q2 : 1.f - q2;
    A      *= ((lane >> 3) & 1) ? q3 : 1.f - q3;
    A      *= ((lane >> 4) & 1) ? q4 : 1.f - q4;
    A      *= ((lane >> 5) & 1) ? q5 : 1.f - q5;

    // E = A * C over dims 6..8 (shared by all quarters)
    const float t6 = 1.f - q6, t7 = 1.f - q7, t8 = 1.f - q8;
    const float u0 = t6 * t7, u1 = q6 * t7, u2 = t6 * q7, u3 = q6 * q7;
    const float E0 = A * (u0 * t8), E1 = A * (u1 * t8), E2 = A * (u2 * t8), E3 = A * (u3 * t8);
    const float E4 = A * (u0 * q8), E5 = A * (u1 * q8), E6 = A * (u2 * q8), E7 = A * (u3 * q8);

    // this wave's two D values: m>>3 = wid*2 {+1}
    const float t9 = 1.f - q9, t10 = 1.f - q10;
    const float vl = (wid & 1) ? ((1.f - q9) * q10) : (t9 * t10);   // v2 : v0
    const float vh = (wid & 1) ? (q9 * q10)          : (q9 * t10);  // v3 : v1
    const float w11 = (wid & 2) ? q11 : (1.f - q11);
    const float Dlo = vl * w11;
    const float Dhi = vh * w11;

    b0  = fmaf(E0, Dlo, b0);  b1  = fmaf(E1, Dlo, b1);  b2  = fmaf(E2, Dlo, b2);  b3  = fmaf(E3, Dlo, b3);
    b4  = fmaf(E4, Dlo, b4);  b5  = fmaf(E5, Dlo, b5);  b6  = fmaf(E6, Dlo, b6);  b7  = fmaf(E7, Dlo, b7);
    b8  = fmaf(E0, Dhi, b8);  b9  = fmaf(E1, Dhi, b9);  b10 = fmaf(E2, Dhi, b10); b11 = fmaf(E3, Dhi, b11);
    b12 = fmaf(E4, Dhi, b12); b13 = fmaf(E5, Dhi, b13); b14 = fmaf(E6, Dhi, b14); b15 = fmaf(E7, Dhi, b15);
  }

  // write this wave's disjoint 16x64 slice of the block's slab (coalesced)
  float* hp = hist_part + (size_t)bid * KCB + (size_t)wid * 1024 + lane;
  hp[ 0*64] = b0;  hp[ 1*64] = b1;  hp[ 2*64] = b2;  hp[ 3*64] = b3;
  hp[ 4*64] = b4;  hp[ 5*64] = b5;  hp[ 6*64] = b6;  hp[ 7*64] = b7;
  hp[ 8*64] = b8;  hp[ 9*64] = b9;  hp[10*64] = b10; hp[11*64] = b11;
  hp[12*64] = b12; hp[13*64] = b13; hp[14*64] = b14; hp[15*64] = b15;

  // pse/com: identical in all 4 waves (same rows) -> commit from wave 0 only
  if (wid == 0) {
#pragma unroll
    for (int ofs = 1; ofs < 64; ofs <<= 1) {
      pse_acc += __shfl_xor(pse_acc, ofs, 64);
      com_acc += __shfl_xor(com_acc, ofs, 64);
    }
    if (lane == 0) { atomicAdd(pse, pse_acc); atomicAdd(com, com_acc); }
  }
}

// ---------- Kernel D1: partial slab reduction (chunked) ----------
__global__ __launch_bounds__(256) void k_hr1(
    const float* __restrict__ hist_part, float* __restrict__ part2,
    int nslab)
{
  const int j     = (blockIdx.x & 15) * 256 + threadIdx.x;
  const int chunk = blockIdx.x >> 4;              // 0..15
  const int per   = nslab >> 4;
  const int b0    = chunk * per;
  float acc = 0.f;
#pragma unroll 4
  for (int b = 0; b < per; ++b)
    acc += hist_part[(size_t)(b0 + b) * KCB + j];
  part2[(size_t)chunk * KCB + j] = acc;
}

// ---------- Kernel D2: final codebook entropy ----------
__global__ __launch_bounds__(256) void k_hr2(
    const float* __restrict__ part2, float* __restrict__ cbe)
{
  const int j = blockIdx.x * 256 + threadIdx.x;
  float acc = 0.f;
#pragma unroll
  for (int c = 0; c < 16; ++c) acc += part2[(size_t)c * KCB + j];
  const float a = acc * (1.f / 16384.f);
  float term = -a * __logf(a + 1e-10f);
#pragma unroll
  for (int ofs = 1; ofs < 64; ofs <<= 1) term += __shfl_xor(term, ofs, 64);
  __shared__ float sw[4];
  if ((threadIdx.x & 63) == 0) sw[threadIdx.x >> 6] = term;
  __syncthreads();
  if (threadIdx.x == 0) atomicAdd(cbe, sw[0] + sw[1] + sw[2] + sw[3]);
}

// ---------- Kernel E: combine scalars ----------
__global__ void k_aux(const float* __restrict__ pse, const float* __restrict__ com,
                      const float* __restrict__ cbe, float* __restrict__ aux)
{
  aux[0] = pse[0] * (1.f / 16384.f) - cbe[0] + com[0] * (1.f / 196608.f);
}

extern "C" void kernel_launch(void* const* d_in, const int* in_sizes, int n_in,
                              void* d_out, int out_size, void* d_ws, size_t ws_size,
                              hipStream_t stream)
{
  const float* x    = (const float*)d_in[0];
  const float* Win  = (const float*)d_in[1];
  const float* bin  = (const float*)d_in[2];
  const float* Wout = (const float*)d_in[3];
  const float* bout = (const float*)d_in[4];

  float* out  = (float*)d_out;                       // [16384 x 1024]
  float* oidx = out + (size_t)M_ROWS * DIMX;         // [16384]
  float* aux  = oidx + M_ROWS;                       // [1]

  float* ws        = (float*)d_ws;
  float* h         = ws;                             // 196608 floats
  float* scal      = ws + (size_t)M_ROWS * CD;       // pse, com, cbe (pad 16)
  float* pse       = scal;
  float* com       = scal + 1;
  float* cbe       = scal + 2;
  float* part2     = scal + 16;                      // 16 * 4096 floats
  float* hist_part = part2 + 16 * KCB;               // nblk * 4096 floats

  // one histogram slab per BLOCK (4 waves write disjoint quarters)
  int nblk = 1024;
  while (nblk > 64 &&
         ((size_t)M_ROWS * CD + 16 + 16 * KCB + (size_t)nblk * KCB) * 4 > ws_size)
    nblk >>= 1;
  const int rpw = M_ROWS / nblk;                     // rows per block (all 4 waves)

  k_hproj<<<512, 256, 0, stream>>>(x, Win, bin, h, oidx, scal);  // also zeroes scal[0..2]
  k_ent  <<<nblk, 256, 0, stream>>>(h, hist_part, pse, com, rpw);   // h still L2-warm
  k_out  <<<512, 256, 0, stream>>>(Wout, bout, oidx, out, M_ROWS / 512);
  k_hr1  <<<256, 256, 0, stream>>>(hist_part, part2, nblk);
  k_hr2  <<<KCB / 256, 256, 0, stream>>>(part2, cbe);
  k_aux  <<<1, 1, 0, stream>>>(pse, com, cbe, aux);
}

// Round 9
// 80.450 us; speedup vs baseline: 5.2840x; 1.2494x over previous
//
#include <hip/hip_runtime.h>

#define M_ROWS 16384
#define DIMX   1024
#define CD     12
#define KCB    4096
#define PADW   60   // padded dwords per float4-position fragment (48 data + 12 pad)
#define NSLAB  512  // one hist slab per k_body block

// ---------- Kernel A: h = x @ W_in + b_in ; writes h and oidx ----------
// Arithmetic (FMA order k,e,d; butterfly ofs 1..32; +bin at end) is bit-identical
// to the round-1/2 version that produced exact index match. Also zeroes the two
// scalar accumulators (pse, com).
__global__ __launch_bounds__(256, 2) void k_hproj(
    const float* __restrict__ x, const float* __restrict__ Win,
    const float* __restrict__ bin, float* __restrict__ h, float* __restrict__ oidx,
    float* __restrict__ scal)
{
  if (blockIdx.x == 0 && threadIdx.x == 0) {
    scal[0] = 0.f; scal[1] = 0.f;   // pse, com
  }

  __shared__ __align__(16) float w[256 * PADW];   // 60 KB
  for (int f = threadIdx.x; f < 256 * 12; f += 256) {
    const int P = f / 12, c = f % 12;
    float4 v = reinterpret_cast<const float4*>(Win)[f];
    *reinterpret_cast<float4*>(&w[P * PADW + 4 * c]) = v;
  }
  __syncthreads();

  const int wave = threadIdx.x >> 6;
  const int lane = threadIdx.x & 63;
  const int g    = blockIdx.x * 4 + wave;         // 0..2047, 8 rows per wave

  float bb[CD];
#pragma unroll
  for (int d = 0; d < CD; ++d) bb[d] = bin[d];

  for (int it = 0; it < 4; ++it) {                // 2 rows per iteration
    const int row0 = g * 8 + it * 2;
    const float4* xr0 = reinterpret_cast<const float4*>(x + (size_t)row0 * DIMX);
    const float4* xr1 = reinterpret_cast<const float4*>(x + (size_t)(row0 + 1) * DIMX);
    float a0[CD], a1[CD];
#pragma unroll
    for (int d = 0; d < CD; ++d) { a0[d] = 0.f; a1[d] = 0.f; }

#pragma unroll
    for (int k = 0; k < 4; ++k) {
      const int P = lane + 64 * k;
      float4 xv0 = xr0[P];
      float4 xv1 = xr1[P];
      const float4* wf = reinterpret_cast<const float4*>(&w[P * PADW]);
      float4 wq[12];
#pragma unroll
      for (int c = 0; c < 12; ++c) wq[c] = wf[c];
      const float* wfl = reinterpret_cast<const float*>(wq);
      float xe0[4] = {xv0.x, xv0.y, xv0.z, xv0.w};
      float xe1[4] = {xv1.x, xv1.y, xv1.z, xv1.w};
#pragma unroll
      for (int e = 0; e < 4; ++e)
#pragma unroll
        for (int d = 0; d < CD; ++d) {
          const float wv = wfl[e * CD + d];
          a0[d] = fmaf(xe0[e], wv, a0[d]);
          a1[d] = fmaf(xe1[e], wv, a1[d]);
        }
    }
#pragma unroll
    for (int ofs = 1; ofs < 64; ofs <<= 1)
#pragma unroll
      for (int d = 0; d < CD; ++d) {
        a0[d] += __shfl_xor(a0[d], ofs, 64);
        a1[d] += __shfl_xor(a1[d], ofs, 64);
      }

    if (lane == 0) {
      int i0 = 0, i1 = 0;
#pragma unroll
      for (int d = 0; d < CD; ++d) {
        const float h0 = a0[d] + bb[d];
        const float h1 = a1[d] + bb[d];
        h[(size_t)row0 * CD + d]       = h0;
        h[(size_t)(row0 + 1) * CD + d] = h1;
        i0 |= (h0 > 0.f) ? (1 << d) : 0;
        i1 |= (h1 > 0.f) ? (1 << d) : 0;
      }
      oidx[row0]     = (float)i0;
      oidx[row0 + 1] = (float)i1;
    }
  }
}

// ---------- Kernel B: fused out-projection + entropy/commit + histogram ----------
// 512 threads, 32 rows per block.
// Phase A: thread owns 2 output cols -> wreg = 24 regs (under the ~56-VGPR RA cap).
// Phase B: 8 waves; wave w owns hist m in [8w, 8w+8) -> ONE D value + 8 named accs
// (~35 live regs). All waves walk the same 32 rows; disjoint coalesced slab writes.
__global__ __launch_bounds__(512) void k_body(
    const float* __restrict__ h, const float* __restrict__ Wout,
    const float* __restrict__ bout, const float* __restrict__ oidx,
    float* __restrict__ out, float* __restrict__ hist_part,
    float* __restrict__ scal)
{
  const int t    = threadIdx.x;          // 0..511
  const int bid  = blockIdx.x;
  const int row0 = bid * 32;

  // ---------------- Phase A: out = sign(h) @ W_out + b_out ----------------
  {
    float w0[CD], w1[CD];
#pragma unroll
    for (int d = 0; d < CD; ++d) {
      float2 v = *reinterpret_cast<const float2*>(Wout + d * DIMX + 2 * t);
      w0[d] = v.x; w1[d] = v.y;
    }
    const float2 b2 = *reinterpret_cast<const float2*>(bout + 2 * t);

    for (int i = 0; i < 32; ++i) {
      const int row = row0 + i;
      const int idx = (int)oidx[row];    // block-uniform scalar load
      float o0 = b2.x, o1 = b2.y;
#pragma unroll
      for (int d = 0; d < CD; ++d) {
        const float s = ((idx >> d) & 1) ? 1.f : -1.f;
        o0 = fmaf(s, w0[d], o0);
        o1 = fmaf(s, w1[d], o1);
      }
      *reinterpret_cast<float2*>(out + (size_t)row * DIMX + 2 * t) = make_float2(o0, o1);
    }
  }

  // ---------------- Phase B: entropy + commit + factorized histogram ----------------
  const int lane = t & 63;
  const int w8   = t >> 6;               // wave id 0..7; m in [8*w8, 8*w8+8)

  float c0=0.f,c1=0.f,c2=0.f,c3=0.f,c4=0.f,c5=0.f,c6=0.f,c7=0.f;
  float pse_acc = 0.f, com_acc = 0.f;

  for (int i = 0; i < 32; ++i) {
    const int row = row0 + i;
    float qv = 0.f;
    if (lane < CD) {
      const float hv = h[(size_t)row * CD + lane];
      const float ax  = fabsf(40.f * hv);
      const float e2  = __expf(-ax);
      const float s1  = 1.f + e2;
      const float inv = 1.f / s1;
      qv = (hv > 0.f) ? inv : e2 * inv;            // sigmoid(40 h)
      pse_acc += __logf(s1) + ax * e2 * inv;       // per-dim entropy term
      const float dd = fabsf(hv) - 1.f;
      com_acc += dd * dd;
    }
    const float q0  = __shfl(qv, 0, 64),  q1  = __shfl(qv, 1, 64);
    const float q2  = __shfl(qv, 2, 64),  q3  = __shfl(qv, 3, 64);
    const float q4  = __shfl(qv, 4, 64),  q5  = __shfl(qv, 5, 64);
    const float q6  = __shfl(qv, 6, 64),  q7  = __shfl(qv, 7, 64);
    const float q8  = __shfl(qv, 8, 64),  q9  = __shfl(qv, 9, 64);
    const float q10 = __shfl(qv, 10, 64), q11 = __shfl(qv, 11, 64);

    // A over the low 6 bits (lane-dependent)
    float A = ((lane >> 0) & 1) ? q0 : 1.f - q0;
    A      *= ((lane >> 1) & 1) ? q1 : 1.f - q1;
    A      *= ((lane >> 2) & 1) ? q2 : 1.f - q2;
    A      *= ((lane >> 3) & 1) ? q3 : 1.f - q3;
    A      *= ((lane >> 4) & 1) ? q4 : 1.f - q4;
    A      *= ((lane >> 5) & 1) ? q5 : 1.f - q5;

    // E = A * C over dims 6..8
    const float t6 = 1.f - q6, t7 = 1.f - q7, t8 = 1.f - q8;
    const float u0 = t6 * t7, u1 = q6 * t7, u2 = t6 * q7, u3 = q6 * q7;
    const float E0 = A * (u0 * t8), E1 = A * (u1 * t8), E2 = A * (u2 * t8), E3 = A * (u3 * t8);
    const float E4 = A * (u0 * q8), E5 = A * (u1 * q8), E6 = A * (u2 * q8), E7 = A * (u3 * q8);

    // this wave's single D value over dims 9..11 (m>>3 == w8)
    const float vw = (((w8 & 1) ? q9 : 1.f - q9) * ((w8 & 2) ? q10 : 1.f - q10));
    const float Dw = vw * ((w8 & 4) ? q11 : 1.f - q11);

    c0 = fmaf(E0, Dw, c0); c1 = fmaf(E1, Dw, c1); c2 = fmaf(E2, Dw, c2); c3 = fmaf(E3, Dw, c3);
    c4 = fmaf(E4, Dw, c4); c5 = fmaf(E5, Dw, c5); c6 = fmaf(E6, Dw, c6); c7 = fmaf(E7, Dw, c7);
  }

  // disjoint coalesced slab write: index = (8*w8 + e)*64 + lane
  float* hp = hist_part + (size_t)bid * KCB + (size_t)w8 * 512 + lane;
  hp[0*64] = c0; hp[1*64] = c1; hp[2*64] = c2; hp[3*64] = c3;
  hp[4*64] = c4; hp[5*64] = c5; hp[6*64] = c6; hp[7*64] = c7;

  // pse/com identical in all 8 waves -> commit from wave 0 only
  if (w8 == 0) {
#pragma unroll
    for (int ofs = 1; ofs < 64; ofs <<= 1) {
      pse_acc += __shfl_xor(pse_acc, ofs, 64);
      com_acc += __shfl_xor(com_acc, ofs, 64);
    }
    if (lane == 0) { atomicAdd(&scal[0], pse_acc); atomicAdd(&scal[1], com_acc); }
  }
}

// ---------- Kernel C: stage-1 slab reduction (128 blocks) ----------
// block b: code range (b&7)*512, chunk (b>>3) of 32 slabs; thread sums 2 codes.
__global__ __launch_bounds__(256) void k_hr1(
    const float* __restrict__ hist_part, float* __restrict__ part2)
{
  const int j0    = (blockIdx.x & 7) * 512 + threadIdx.x;
  const int chunk = blockIdx.x >> 3;              // 0..15
  const int s0    = chunk * (NSLAB / 16);
  float acc0 = 0.f, acc1 = 0.f;
#pragma unroll 4
  for (int s = 0; s < NSLAB / 16; ++s) {
    const float* hp = hist_part + (size_t)(s0 + s) * KCB;
    acc0 += hp[j0];
    acc1 += hp[j0 + 256];
  }
  part2[(size_t)chunk * KCB + j0]       = acc0;
  part2[(size_t)chunk * KCB + j0 + 256] = acc1;
}

// ---------- Kernel D: final codebook entropy + aux (single block) ----------
__global__ __launch_bounds__(256) void k_fin(
    const float* __restrict__ part2, const float* __restrict__ scal,
    float* __restrict__ aux)
{
  const int t = threadIdx.x;
  float term = 0.f;
#pragma unroll
  for (int k = 0; k < 16; ++k) {
    const int j = t + 256 * k;
    float a = 0.f;
#pragma unroll
    for (int c = 0; c < 16; ++c) a += part2[(size_t)c * KCB + j];
    a *= (1.f / 16384.f);
    term -= a * __logf(a + 1e-10f);
  }
#pragma unroll
  for (int ofs = 1; ofs < 64; ofs <<= 1) term += __shfl_xor(term, ofs, 64);
  __shared__ float sw[4];
  if ((t & 63) == 0) sw[t >> 6] = term;
  __syncthreads();
  if (t == 0) {
    const float cbe = sw[0] + sw[1] + sw[2] + sw[3];
    aux[0] = scal[0] * (1.f / 16384.f) - cbe + scal[1] * (1.f / 196608.f);
  }
}

extern "C" void kernel_launch(void* const* d_in, const int* in_sizes, int n_in,
                              void* d_out, int out_size, void* d_ws, size_t ws_size,
                              hipStream_t stream)
{
  const float* x    = (const float*)d_in[0];
  const float* Win  = (const float*)d_in[1];
  const float* bin  = (const float*)d_in[2];
  const float* Wout = (const float*)d_in[3];
  const float* bout = (const float*)d_in[4];

  float* out  = (float*)d_out;                       // [16384 x 1024]
  float* oidx = out + (size_t)M_ROWS * DIMX;         // [16384]
  float* aux  = oidx + M_ROWS;                       // [1]

  float* ws        = (float*)d_ws;
  float* h         = ws;                             // 196608 floats
  float* scal      = ws + (size_t)M_ROWS * CD;       // pse, com (pad 16)
  float* part2     = scal + 16;                      // 16 * 4096 floats
  float* hist_part = part2 + 16 * KCB;               // NSLAB * 4096 floats

  k_hproj<<<512, 256, 0, stream>>>(x, Win, bin, h, oidx, scal);
  k_body <<<NSLAB, 512, 0, stream>>>(h, Wout, bout, oidx, out, hist_part, scal);
  k_hr1  <<<128, 256, 0, stream>>>(hist_part, part2);
  k_fin  <<<1, 256, 0, stream>>>(part2, scal, aux);
}